// Round 3
// baseline (341.593 us; speedup 1.0000x reference)
//
#include <hip/hip_runtime.h>
#include <hip/hip_bf16.h>

// Problem constants
#define OUT_H 14
#define OUT_W 14
#define C_CH  256
#define SRC_H 200
#define SRC_W 304
#define M_ROI 1024
#define PLANE   (SRC_H * SRC_W)       // 60800
#define OUT_HW  (OUT_H * OUT_W)       // 196

// Channel-major decomposition: grid = CG_N (outer) x M_ROI (inner).
// All concurrently-resident blocks then share one CG_CH-channel source slab
// (16 ch x 4 img x 243KB = ~15.6 MB) -> L3-resident -> each line fetched ~once.
#define CG_N    16
#define CG_CH   (C_CH / CG_N)         // 16 channels per block

// Sampled-column span bound: roi side <= 69, extended *1.1 -> span <= 74.9,
// so wc = col[13]+2-col[0] <= 76. Use 80.
#define WC_MAX  80
#define STRIP_SZ (OUT_H * 2 * WC_MAX) // 2240 floats per buffer
#define NSLOT   9                     // ceil(2240/256)

__global__ __launch_bounds__(256) void roi_crop_kernel(
    const float* __restrict__ src,
    const float* __restrict__ rois,
    float* __restrict__ out)
{
    const int bid = blockIdx.x;
    const int cg  = bid >> 10;            // channel-group: OUTER
    const int m   = bid & (M_ROI - 1);    // roi: INNER
    const int t   = threadIdx.x;

    __shared__ float strip[2][STRIP_SZ];  // double-buffered row strips
    __shared__ int   s_row[OUT_H];        // clamped r0 * SRC_W
    __shared__ float s_wy[OUT_H];         // wy with boundary fold (may be 1.x)
    __shared__ int   s_col[OUT_W];        // clamped x0 (monotone non-decreasing)
    __shared__ float s_wx[OUT_W];
    __shared__ int   s_b;

    if (t < OUT_H + OUT_W) {
        float bf = rois[m * 5 + 0];
        float x1 = rois[m * 5 + 1];
        float y1 = rois[m * 5 + 2];
        float x2 = rois[m * 5 + 3];
        float y2 = rois[m * 5 + 4];

        // KEEP_AR, _AR = 1.0
        float h  = y2 - y1 + 1.0f;
        float w  = x2 - x1 + 1.0f;
        float ew = (h - w) * 0.5f;
        float eh = (w - h) * 0.5f;
        if (ew > 0.0f) { x1 -= ew; x2 += ew; }
        else           { y1 -= eh; y2 += eh; }

        // EXTEND_RATIO = 0.1 -> each side + size*0.05
        float sw = x2 - x1 + 1.0f;
        float sh = y2 - y1 + 1.0f;
        x1 -= sw * 0.05f; x2 += sw * 0.05f;
        y1 -= sh * 0.05f; y2 += sh * 0.05f;

        if (t < OUT_H) {
            float ty = (float)t / (float)(OUT_H - 1);
            float ys = y1 + (y2 - y1) * ty;
            ys = fminf(fmaxf(ys, 0.0f), (float)(SRC_H - 1));
            float y0f = floorf(ys);
            int   y0  = (int)y0f;
            s_row[t] = min(y0, SRC_H - 2) * SRC_W;               // rows r, r+1 always valid
            s_wy[t]  = (ys - y0f) + (y0 > SRC_H - 2 ? 1.0f : 0.0f);
        } else {
            int i = t - OUT_H;
            float tx = (float)i / (float)(OUT_W - 1);
            float xs = x1 + (x2 - x1) * tx;
            xs = fminf(fmaxf(xs, 0.0f), (float)(SRC_W - 1));
            float x0f = floorf(xs);
            int   x0  = (int)x0f;
            s_col[i] = min(x0, SRC_W - 2);                       // cols c, c+1 always valid
            s_wx[i]  = (xs - x0f) + (x0 > SRC_W - 2 ? 1.0f : 0.0f);
        }
        if (t == 0) s_b = (int)bf;
    }
    __syncthreads();

    // Strip geometry (uniform per block)
    const int xlo   = s_col[0];
    const unsigned wc = (unsigned)(s_col[OUT_W - 1] + 2 - xlo);  // 2..76
    const int total = OUT_H * 2 * (int)wc;

    // Per-thread staging slots (constant across channels): LDS offset is
    // linear (t + j*256); global offset within a channel plane is goff[j].
    int goff[NSLOT];
#pragma unroll
    for (int j = 0; j < NSLOT; ++j) {
        unsigned idx = (unsigned)t + (unsigned)j * 256u;
        if ((int)idx < total) {
            unsigned seg = idx / wc;           // seg = oy*2 + half
            unsigned col = idx - seg * wc;
            goff[j] = s_row[seg >> 1] + (int)(seg & 1u) * SRC_W + xlo + (int)col;
        } else {
            goff[j] = -1;
        }
    }

    // Per-thread compute constants
    const bool act = (t < OUT_HW);
    const int  tt  = act ? t : 0;
    const int  oy  = tt / OUT_W;
    const int  ox  = tt - oy * OUT_W;
    const float wy = s_wy[oy];
    const float wx = s_wx[ox];
    const int  cx  = s_col[ox] - xlo;
    const int  rb0 = oy * 2 * (int)wc + cx;
    const int  rb1 = rb0 + (int)wc;

    const float* __restrict__ srcC =
        src + ((size_t)s_b * C_CH + (size_t)cg * CG_CH) * PLANE;
    float* __restrict__ outP =
        out + ((size_t)m * C_CH + (size_t)cg * CG_CH) * OUT_HW + t;

    // Prologue: stage channel 0 of this group into buffer 0.
#pragma unroll
    for (int j = 0; j < NSLOT; ++j)
        if (goff[j] >= 0) strip[0][t + j * 256] = srcC[goff[j]];
    __syncthreads();

    for (int cc = 0; cc < CG_CH; ++cc) {
        // Stage next channel into the other buffer (overlaps compute below).
        if (cc + 1 < CG_CH) {
            const float* __restrict__ srcN = srcC + (size_t)(cc + 1) * PLANE;
            float* dst = strip[(cc + 1) & 1];
#pragma unroll
            for (int j = 0; j < NSLOT; ++j)
                if (goff[j] >= 0) dst[t + j * 256] = srcN[goff[j]];
        }
        // Bilinear from LDS for current channel.
        if (act) {
            const float* sb = strip[cc & 1];
            float v00 = sb[rb0], v01 = sb[rb0 + 1];
            float v10 = sb[rb1], v11 = sb[rb1 + 1];
            float top = v00 + (v01 - v00) * wx;
            float bot = v10 + (v11 - v10) * wx;
            // Nontemporal: don't let 205MB of writes evict the source slab from L3.
            __builtin_nontemporal_store(top + (bot - top) * wy, outP + cc * OUT_HW);
        }
        __syncthreads();   // staging done + strip reads done before reuse
    }
}

extern "C" void kernel_launch(void* const* d_in, const int* in_sizes, int n_in,
                              void* d_out, int out_size, void* d_ws, size_t ws_size,
                              hipStream_t stream)
{
    const float* src  = (const float*)d_in[0];
    const float* rois = (const float*)d_in[1];
    float* out = (float*)d_out;

    dim3 grid(CG_N * M_ROI);
    dim3 block(256);
    roi_crop_kernel<<<grid, block, 0, stream>>>(src, rois, out);
}

// Round 4
// 308.866 us; speedup vs baseline: 1.1060x; 1.1060x over previous
//
#include <hip/hip_runtime.h>
#include <hip/hip_bf16.h>

// Problem constants
#define OUT_H 14
#define OUT_W 14
#define C_CH  256
#define SRC_H 200
#define SRC_W 304
#define M_ROI 1024
#define PLANE   (SRC_H * SRC_W)       // 60800
#define OUT_HW  (OUT_H * OUT_W)       // 196

// Channel-group-outer decomposition: grid = CG_N (outer) x M_ROI (inner).
// Concurrent blocks (~2048) share ~2 channel-slabs (2 x 62 MB) -> L3-resident,
// so each source line is fetched from HBM ~once per phase.
#define CG_N    4
#define CG_CH   (C_CH / CG_N)         // 64 channels per block
#define ELEMS   (CG_CH * OUT_HW)      // 12544 per block
#define ITERS   (ELEMS / 256)         // 49, exact

typedef float f2 __attribute__((ext_vector_type(2), aligned(4)));

__global__ __launch_bounds__(256) void roi_crop_kernel(
    const float* __restrict__ src,
    const float* __restrict__ rois,
    float* __restrict__ out)
{
    const int bid = blockIdx.x;
    const int cg  = bid >> 10;            // channel group: OUTER
    const int m   = bid & (M_ROI - 1);    // roi: INNER
    const int t   = threadIdx.x;

    // Per-pixel table: {bitcast(row0*304 + col0), wx, wy, unused}
    // Clamp folded: row base = min(y0,198)*304 with wy += (y0==199);
    //               col base = min(x0,302)     with wx += (x0==303).
    // Taps are then always p[0], p[1], p[304], p[305] (in-bounds).
    __shared__ float4 tbl[OUT_HW];
    __shared__ int    s_b;

    if (t < OUT_HW) {
        float bf = rois[m * 5 + 0];
        float x1 = rois[m * 5 + 1];
        float y1 = rois[m * 5 + 2];
        float x2 = rois[m * 5 + 3];
        float y2 = rois[m * 5 + 4];

        // KEEP_AR, _AR = 1.0
        float h  = y2 - y1 + 1.0f;
        float w  = x2 - x1 + 1.0f;
        float ew = (h - w) * 0.5f;
        float eh = (w - h) * 0.5f;
        if (ew > 0.0f) { x1 -= ew; x2 += ew; }
        else           { y1 -= eh; y2 += eh; }

        // EXTEND_RATIO = 0.1 -> each side + size*0.05
        float sw = x2 - x1 + 1.0f;
        float sh = y2 - y1 + 1.0f;
        x1 -= sw * 0.05f; x2 += sw * 0.05f;
        y1 -= sh * 0.05f; y2 += sh * 0.05f;

        const int oy = t / OUT_W;
        const int ox = t - oy * OUT_W;

        float ty = (float)oy * (1.0f / (OUT_H - 1));
        float ys = y1 + (y2 - y1) * ty;
        ys = fminf(fmaxf(ys, 0.0f), (float)(SRC_H - 1));
        float y0f = floorf(ys);
        int   y0  = (int)y0f;
        int   rb  = min(y0, SRC_H - 2) * SRC_W;
        float wy  = (ys - y0f) + (y0 > SRC_H - 2 ? 1.0f : 0.0f);

        float tx = (float)ox * (1.0f / (OUT_W - 1));
        float xs = x1 + (x2 - x1) * tx;
        xs = fminf(fmaxf(xs, 0.0f), (float)(SRC_W - 1));
        float x0f = floorf(xs);
        int   x0  = (int)x0f;
        int   cb  = min(x0, SRC_W - 2);
        float wx  = (xs - x0f) + (x0 > SRC_W - 2 ? 1.0f : 0.0f);

        tbl[t] = make_float4(__int_as_float(rb + cb), wx, wy, 0.0f);
        if (t == 0) s_b = (int)bf;
    }
    __syncthreads();

    const float* __restrict__ srcB =
        src + ((size_t)s_b * C_CH + (size_t)cg * CG_CH) * PLANE;
    float* __restrict__ outB =
        out + (size_t)m * (C_CH * OUT_HW) + (size_t)cg * ELEMS;

#pragma unroll 1
    for (int k = 0; k < ITERS; ++k) {
        unsigned flat = (unsigned)(t + k * 256);
        unsigned c    = flat / 196u;              // magic-mul
        unsigned p    = flat - c * 196u;

        float4 e  = tbl[p];                       // one ds_read_b128
        int   off = __float_as_int(e.x);
        float wx  = e.y;
        float wy  = e.z;

        const float* ptr = srcB + (size_t)c * PLANE + off;
        f2 top = *(const f2*)ptr;                 // taps (r0,c0),(r0,c0+1)
        f2 bot = *(const f2*)(ptr + SRC_W);       // taps (r1,c0),(r1,c0+1)

        float tv = top.x + (top.y - top.x) * wx;
        float bv = bot.x + (bot.y - bot.x) * wx;
        __builtin_nontemporal_store(tv + (bv - tv) * wy, outB + flat);
    }
}

extern "C" void kernel_launch(void* const* d_in, const int* in_sizes, int n_in,
                              void* d_out, int out_size, void* d_ws, size_t ws_size,
                              hipStream_t stream)
{
    const float* src  = (const float*)d_in[0];
    const float* rois = (const float*)d_in[1];
    float* out = (float*)d_out;

    dim3 grid(CG_N * M_ROI);
    dim3 block(256);
    roi_crop_kernel<<<grid, block, 0, stream>>>(src, rois, out);
}

// Round 5
// 110.657 us; speedup vs baseline: 3.0870x; 2.7912x over previous
//
#include <hip/hip_runtime.h>
#include <hip/hip_bf16.h>

// Problem constants
#define OUT_H 14
#define OUT_W 14
#define C_CH  256
#define SRC_H 200
#define SRC_W 304
#define M_ROI 1024
#define PLANE   (SRC_H * SRC_W)       // 60800
#define OUT_HW  (OUT_H * OUT_W)       // 196

// One block = (1 channel, ROIS_PB rois). Grid ordered so each XCD works
// through its 32 channels sequentially; resident window ~2-3 channel-sets
// (4 images x 243KB each) stays L2-resident -> cross-roi line reuse in L2.
#define ROIS_PB 8
#define CHUNKS  (M_ROI / ROIS_PB)     // 128
#define NXCD    8
#define CH_PER_XCD (C_CH / NXCD)      // 32
#define ELEMS   (ROIS_PB * OUT_HW)    // 1568
#define NITER   ((ELEMS + 255) / 256) // 7 (last partial)

typedef float f2 __attribute__((ext_vector_type(2), aligned(4)));

__global__ __launch_bounds__(256) void roi_crop_kernel(
    const float* __restrict__ src,
    const float* __restrict__ rois,
    float* __restrict__ out)
{
    const int bid = blockIdx.x;
    // XCD-aware decode: hardware round-robins bid % 8 across XCDs.
    // XCD x receives j = bid>>3 in order; channel changes every 128 blocks.
    const int x     = bid & (NXCD - 1);
    const int j     = bid >> 3;              // 0..4095 per XCD
    const int c     = x * CH_PER_XCD + (j >> 7);
    const int chunk = j & (CHUNKS / NXCD == 0 ? 0 : 127); // j % 128
    const int roi0  = chunk * ROIS_PB;
    const int t     = threadIdx.x;

    // Per-roi separable tables; clamp folded into (base, weight):
    //  row: base=min(y0,198)*304, wy += (y0==199)  -> taps rows r,r+1 valid
    //  col: base=min(x0,302),     wx += (x0==303)  -> taps cols c,c+1 valid
    __shared__ int   s_row[ROIS_PB * OUT_H];
    __shared__ float s_wy [ROIS_PB * OUT_H];
    __shared__ int   s_col[ROIS_PB * OUT_W];
    __shared__ float s_wx [ROIS_PB * OUT_W];
    __shared__ int   s_pbase[ROIS_PB];       // (b*256 + c) * PLANE

    if (t < ROIS_PB * (OUT_H + OUT_W)) {     // 224 threads
        const int r = t / (OUT_H + OUT_W);
        const int e = t - r * (OUT_H + OUT_W);
        const int rm = roi0 + r;

        float bf = rois[rm * 5 + 0];
        float x1 = rois[rm * 5 + 1];
        float y1 = rois[rm * 5 + 2];
        float x2 = rois[rm * 5 + 3];
        float y2 = rois[rm * 5 + 4];

        // KEEP_AR, _AR = 1.0
        float h  = y2 - y1 + 1.0f;
        float w  = x2 - x1 + 1.0f;
        float ew = (h - w) * 0.5f;
        float eh = (w - h) * 0.5f;
        if (ew > 0.0f) { x1 -= ew; x2 += ew; }
        else           { y1 -= eh; y2 += eh; }

        // EXTEND_RATIO = 0.1 -> each side + size*0.05
        float sw = x2 - x1 + 1.0f;
        float sh = y2 - y1 + 1.0f;
        x1 -= sw * 0.05f; x2 += sw * 0.05f;
        y1 -= sh * 0.05f; y2 += sh * 0.05f;

        if (e < OUT_H) {
            float ty = (float)e * (1.0f / (OUT_H - 1));
            float ys = y1 + (y2 - y1) * ty;
            ys = fminf(fmaxf(ys, 0.0f), (float)(SRC_H - 1));
            float y0f = floorf(ys);
            int   y0  = (int)y0f;
            s_row[r * OUT_H + e] = min(y0, SRC_H - 2) * SRC_W;
            s_wy [r * OUT_H + e] = (ys - y0f) + (y0 > SRC_H - 2 ? 1.0f : 0.0f);
            if (e == 0) s_pbase[r] = ((int)bf * C_CH + c) * PLANE;
        } else {
            int i = e - OUT_H;
            float tx = (float)i * (1.0f / (OUT_W - 1));
            float xs = x1 + (x2 - x1) * tx;
            xs = fminf(fmaxf(xs, 0.0f), (float)(SRC_W - 1));
            float x0f = floorf(xs);
            int   x0  = (int)x0f;
            s_col[r * OUT_W + i] = min(x0, SRC_W - 2);
            s_wx [r * OUT_W + i] = (xs - x0f) + (x0 > SRC_W - 2 ? 1.0f : 0.0f);
        }
    }
    __syncthreads();

#pragma unroll
    for (int k = 0; k < NITER; ++k) {
        int idx = t + k * 256;
        if (idx < ELEMS) {
            unsigned u  = (unsigned)idx;
            unsigned r  = u / 196u;            // roi-local (magic-mul)
            unsigned p  = u - r * 196u;
            unsigned oy = p / 14u;
            unsigned ox = p - oy * 14u;

            const float* ptr = src + s_pbase[r]
                             + s_row[r * OUT_H + oy] + s_col[r * OUT_W + ox];
            float wx = s_wx[r * OUT_W + ox];
            float wy = s_wy[r * OUT_H + oy];

            f2 top = *(const f2*)ptr;            // (r0,c0),(r0,c0+1)
            f2 bot = *(const f2*)(ptr + SRC_W);  // (r1,c0),(r1,c0+1)

            float tv = top.x + (top.y - top.x) * wx;
            float bv = bot.x + (bot.y - bot.x) * wx;

            size_t o = ((size_t)(roi0 + (int)r) * C_CH + (size_t)c) * OUT_HW + p;
            __builtin_nontemporal_store(tv + (bv - tv) * wy, out + o);
        }
    }
}

extern "C" void kernel_launch(void* const* d_in, const int* in_sizes, int n_in,
                              void* d_out, int out_size, void* d_ws, size_t ws_size,
                              hipStream_t stream)
{
    const float* src  = (const float*)d_in[0];
    const float* rois = (const float*)d_in[1];
    float* out = (float*)d_out;

    dim3 grid(C_CH * CHUNKS);   // 32768 blocks = 8 XCD x 32 ch x 128 chunks
    dim3 block(256);
    roi_crop_kernel<<<grid, block, 0, stream>>>(src, rois, out);
}